// Round 3
// baseline (522.188 us; speedup 1.0000x reference)
//
#include <hip/hip_runtime.h>

#define NN 1024
#define BB 32
#define DD 128
#define EPSF 1e-6f
#define CAP 16384
#define NNNN ((size_t)NN * NN)

typedef __bf16 bf16x8 __attribute__((ext_vector_type(8)));
typedef float  f32x4  __attribute__((ext_vector_type(4)));
typedef unsigned short u16x8 __attribute__((ext_vector_type(8)));

typedef __attribute__((address_space(3))) unsigned int lds_u32;
typedef __attribute__((address_space(1))) const unsigned int glb_u32;

__device__ __forceinline__ lds_u32* lds_cast(const void* p) {
  return (lds_u32*)(unsigned int)(unsigned long long)p;
}
__device__ __forceinline__ glb_u32* glb_cast(const void* p) {
  return (glb_u32*)(unsigned long long)p;
}

__device__ __forceinline__ float bf2f(unsigned short u) {
  union { unsigned int i; float f; } v; v.i = ((unsigned int)u) << 16; return v.f;
}
__device__ __forceinline__ unsigned short f2bf(float f) {
  union { float f; unsigned int i; } v; v.f = f;
  unsigned int r = v.i + 0x7fffu + ((v.i >> 16) & 1u);
  return (unsigned short)(r >> 16);
}

// ---------------- convert / transpose kernels ----------------

__global__ __launch_bounds__(256) void convert_wp(const float* __restrict__ src,
    unsigned short* __restrict__ Wp, unsigned short* __restrict__ WpT) {
  __shared__ float tile[64][65];
  const int b = blockIdx.z;
  const int c0 = blockIdx.x * 64, r0 = blockIdx.y * 64;
  const int t = threadIdx.x;
  const int rr = t >> 3, cb = (t & 7) * 8;
  const size_t base = (size_t)b * NNNN;
#pragma unroll
  for (int p = 0; p < 2; ++p) {
    const int r = rr + p * 32;
    const float* srow = src + base + (size_t)(r0 + r) * NN + c0 + cb;
    f32x4 v0 = *(const f32x4*)srow;
    f32x4 v1 = *(const f32x4*)(srow + 4);
    u16x8 w;
#pragma unroll
    for (int j = 0; j < 4; ++j) { w[j] = f2bf(v0[j]); w[4 + j] = f2bf(v1[j]); }
    *(u16x8*)(Wp + base + (size_t)(r0 + r) * NN + c0 + cb) = w;
#pragma unroll
    for (int j = 0; j < 4; ++j) { tile[r][cb + j] = v0[j]; tile[r][cb + 4 + j] = v1[j]; }
  }
  __syncthreads();
#pragma unroll
  for (int p = 0; p < 2; ++p) {
    const int r = rr + p * 32;
    u16x8 w;
#pragma unroll
    for (int j = 0; j < 8; ++j) w[j] = f2bf(tile[cb + j][r]);
    *(u16x8*)(WpT + base + (size_t)(c0 + r) * NN + r0 + cb) = w;
  }
}

__global__ __launch_bounds__(256) void convert_x(const float* __restrict__ x,
    unsigned short* __restrict__ xT) {
  __shared__ float tile[32][33];
  const int b = blockIdx.z;
  const int d0 = blockIdx.x * 32, n0 = blockIdx.y * 32;
  const int tx = threadIdx.x, ty = threadIdx.y;
#pragma unroll
  for (int s = 0; s < 4; ++s) {
    int rr = ty + s * 8;
    tile[rr][tx] = x[(size_t)b * NN * DD + (size_t)(n0 + rr) * DD + d0 + tx];
  }
  __syncthreads();
#pragma unroll
  for (int s = 0; s < 4; ++s) {
    int rr = ty + s * 8;
    xT[(size_t)b * DD * NN + (size_t)(d0 + rr) * NN + n0 + tx] = f2bf(tile[tx][rr]);
  }
}

// adj -> mcode bit0 (= adj[j,i]==1 at [i,j]), adj_bf, adjT_bf
__global__ __launch_bounds__(256) void mask0cvt(const float* __restrict__ adj,
    unsigned char* __restrict__ mcode, unsigned short* __restrict__ adjbf,
    unsigned short* __restrict__ adjTbf) {
  __shared__ float tile[32][33];
  const int i0 = blockIdx.x * 32, j0 = blockIdx.y * 32;
  const int tx = threadIdx.x, ty = threadIdx.y;
#pragma unroll
  for (int s = 0; s < 4; ++s) {
    int rr = ty + s * 8;
    float v = adj[(size_t)(j0 + rr) * NN + i0 + tx];
    adjbf[(size_t)(j0 + rr) * NN + i0 + tx] = f2bf(v);
    tile[rr][tx] = v;
  }
  __syncthreads();
#pragma unroll
  for (int s = 0; s < 4; ++s) {
    int rr = ty + s * 8;
    float v = tile[tx][rr];
    adjTbf[(size_t)(i0 + rr) * NN + j0 + tx] = f2bf(v);
    mcode[(size_t)(i0 + rr) * NN + j0 + tx] = (v == 1.0f) ? 1 : 0;
  }
}

// sum 4 K-split partials (exact ints) -> A2 bf16, A2T bf16, mcode bit1 where ==1
__global__ __launch_bounds__(256) void scan_a2(const float* __restrict__ P,
    unsigned short* __restrict__ A2, unsigned short* __restrict__ A2T,
    unsigned char* __restrict__ mcode) {
  __shared__ float tile[32][33];
  const int m0 = blockIdx.x * 32, n0 = blockIdx.y * 32;
  const int tx = threadIdx.x, ty = threadIdx.y;
#pragma unroll
  for (int s = 0; s < 4; ++s) {
    int rr = ty + s * 8;
    size_t idx = (size_t)(m0 + rr) * NN + n0 + tx;
    float v = P[idx] + P[NNNN + idx] + P[2 * NNNN + idx] + P[3 * NNNN + idx];
    A2[idx] = f2bf(v);
    tile[rr][tx] = v;
  }
  __syncthreads();
#pragma unroll
  for (int s = 0; s < 4; ++s) {
    int rr = ty + s * 8;
    float v = tile[tx][rr];
    A2T[(size_t)(n0 + rr) * NN + m0 + tx] = f2bf(v);
    if (v == 1.0f) mcode[(size_t)(n0 + rr) * NN + m0 + tx] |= 2;
  }
}

// sum 4 partials of A^4; record entries (m<<16)|n where ==1.0
__global__ __launch_bounds__(256) void scan_a4(const float* __restrict__ P,
    unsigned int* __restrict__ entries, int* __restrict__ nnz) {
  size_t e = (size_t)blockIdx.x * 256 + threadIdx.x;
  float v = P[e] + P[NNNN + e] + P[2 * NNNN + e] + P[3 * NNNN + e];
  if (v == 1.0f) {
    int idx = atomicAdd(nnz, 1);
    if (idx < CAP) entries[idx] = ((unsigned)(e >> 10) << 16) | (unsigned)(e & 1023);
  }
}

// ---------------- MFMA GEMM tiles ----------------
// C[m,n] = sum_k A[m,k]*B[n,k].

struct EpiWcomb {  // mask2-gated bf16 write
  const unsigned char* mc;
  unsigned short* out;
  __device__ __forceinline__ void operator()(int b, int ks, int i, int j, float v) const {
    size_t idx = (size_t)i * NN + j;
    out[(size_t)b * NNNN + idx] = (mc[idx] & 2) ? f2bf(v) : (unsigned short)0;
  }
};

struct EpiSqPart {  // K-split partial, plain store
  float* buf;
  __device__ __forceinline__ void operator()(int b, int ks, int i, int j, float v) const {
    buf[(size_t)ks * NNNN + (size_t)i * NN + j] = v;
  }
};

struct EpiAggPart {  // 2-way K-split partials (p0 = d_out, p1 = ws)
  float* p0;
  float* p1;
  __device__ __forceinline__ void operator()(int b, int ks, int i, int d, float v) const {
    (ks ? p1 : p0)[(size_t)b * NN * DD + (size_t)i * DD + d] = v;
  }
};

#define LGKM_BARRIER() do { \
  asm volatile("s_waitcnt lgkmcnt(0)" ::: "memory"); \
  __builtin_amdgcn_s_barrier(); \
  asm volatile("" ::: "memory"); } while (0)

// ---- LDS-traffic-minimized GEMM: the previous 128x128/4x4 structure was
// LDS-BW-bound at the 128 B/cyc/CU hardware peak (reads 96KB + DMA writes
// 48KB per 1125-cyc K-window; MfmaUtil 23% matched that accounting exactly).
// This version halves LDS bytes/FLOP: (a) 8x4 fragment blocking per wave
// (tile 256x128, wave tile 128x64, a-frag reads amortized over 4x more MFMA),
// (b) B operand is read DIRECTLY from global (L2-resident via XCD swizzle)
// into registers — no B LDS reads, no B DMA writes. Only A is DMA-staged,
// double-buffered, with the proven granule XOR swizzle (2-way = free).
#define GBM 256
#define GBN 128
#define GBK 32

template <int MW, typename Epi>
__global__ __launch_bounds__(256, MW) void gemm_big(
    const unsigned short* __restrict__ Ap, size_t sA,
    const unsigned short* __restrict__ Bp, size_t sB,
    int swz, int ksN, int nit, Epi epi) {
  __shared__ __align__(16) unsigned short As[2 * GBM * GBK];  // 32 KB
  int bx = blockIdx.x, by = blockIdx.y, z = blockIdx.z;
  if (swz == 2) {  // batch->XCD co-location; grid (4,8,Z): lin = bx + 4*by + 32*z
    int lin = bx + (by << 2) + (z << 5);
    int xcd = lin & 7, rest = lin >> 3;
    z = (xcd << 2) + (rest >> 5);   // 4 batches per XCD
    int tile = rest & 31;
    bx = tile & 3; by = tile >> 2;
  }
  const int b = z / ksN, ks = z - b * ksN;
  const int kbase = ks * nit * GBK;
  const int tm = bx * GBM, tn = by * GBN;
  const unsigned short* Ab = Ap + (size_t)b * sA;
  const unsigned short* Bb = Bp + (size_t)b * sB;
  const int tid = threadIdx.x;
  const int w = tid >> 6, l = tid & 63;
  const int fr = l & 15, quad = l >> 4;
  const int wm = w >> 1, wn = w & 1;
  const int moff = wm * 128, noff = wn * 64;

  // A staging: 4 global_load_lds x 16B per thread per slot (256 rows x 64B).
  // LDS dest linear (wave-uniform base + lane*16); global src pre-swizzled
  // so LDS row r granule gpos holds global granule gpos ^ ((r>>1)&3).
  const int srow = l >> 2, gpos = l & 3;
  const unsigned short* gA[4];
#pragma unroll
  for (int i = 0; i < 4; ++i) {
    int r = i * 64 + w * 16 + srow;
    int g = gpos ^ ((r >> 1) & 3);
    gA[i] = Ab + (size_t)(tm + r) * NN + kbase + g * 8;
  }
  unsigned short* const As0 = As;
  unsigned short* const As1 = As + GBM * GBK;

  // B fragment base addresses (per ni), read straight from global/L2.
  const size_t bo0 = (size_t)(tn + noff + 0 * 16 + fr) * NN + kbase + quad * 8;
  const size_t bo1 = (size_t)(tn + noff + 1 * 16 + fr) * NN + kbase + quad * 8;
  const size_t bo2 = (size_t)(tn + noff + 2 * 16 + fr) * NN + kbase + quad * 8;
  const size_t bo3 = (size_t)(tn + noff + 3 * 16 + fr) * NN + kbase + quad * 8;

  f32x4 acc[8][4];
#pragma unroll
  for (int mi = 0; mi < 8; ++mi)
#pragma unroll
    for (int ni = 0; ni < 4; ++ni) acc[mi][ni] = (f32x4){0.f, 0.f, 0.f, 0.f};

  struct BReg { bf16x8 v0, v1, v2, v3; };
  BReg B0, B1;  // two NAMED sets (static indexing only)

  auto stageA = [&](unsigned short* Asl, int kt) {
    const size_t kk = (size_t)kt * GBK;
#pragma unroll
    for (int i = 0; i < 4; ++i) {
      lds_u32* dst = lds_cast(Asl + (i * 64 + w * 16) * GBK);
      __builtin_amdgcn_global_load_lds(glb_cast(gA[i] + kk), dst, 16, 0, 0);
    }
  };
  auto loadB = [&](BReg& R, int kt) {
    const size_t kk = (size_t)kt * GBK;
    R.v0 = *(const bf16x8*)(Bb + bo0 + kk);
    R.v1 = *(const bf16x8*)(Bb + bo1 + kk);
    R.v2 = *(const bf16x8*)(Bb + bo2 + kk);
    R.v3 = *(const bf16x8*)(Bb + bo3 + kk);
  };
  auto compute = [&](const unsigned short* Ad, const BReg& R) {
    bf16x8 af[8];
#pragma unroll
    for (int mi = 0; mi < 8; ++mi) {
      int r = moff + mi * 16 + fr;
      int kc = quad ^ ((r >> 1) & 3);
      af[mi] = *(const bf16x8*)(Ad + r * GBK + kc * 8);
    }
#pragma unroll
    for (int mi = 0; mi < 8; ++mi) {
      acc[mi][0] = __builtin_amdgcn_mfma_f32_16x16x32_bf16(af[mi], R.v0, acc[mi][0], 0, 0, 0);
      acc[mi][1] = __builtin_amdgcn_mfma_f32_16x16x32_bf16(af[mi], R.v1, acc[mi][1], 0, 0, 0);
      acc[mi][2] = __builtin_amdgcn_mfma_f32_16x16x32_bf16(af[mi], R.v2, acc[mi][2], 0, 0, 0);
      acc[mi][3] = __builtin_amdgcn_mfma_f32_16x16x32_bf16(af[mi], R.v3, acc[mi][3], 0, 0, 0);
    }
  };

  // prologue: tile 0 -> slot0 + B0
  stageA(As0, 0);
  loadB(B0, 0);
  __syncthreads();
#pragma unroll 1
  for (int kt = 0; kt < nit; kt += 2) {
    if (kt + 1 < nit) { stageA(As1, kt + 1); loadB(B1, kt + 1); }
    __builtin_amdgcn_sched_barrier(0);   // keep prefetch issue above MFMA cluster
    compute(As0, B0);                    // tile kt
    __syncthreads();                     // drain lands AFTER compute
    if (kt + 1 < nit) {
      if (kt + 2 < nit) { stageA(As0, kt + 2); loadB(B0, kt + 2); }
      __builtin_amdgcn_sched_barrier(0);
      compute(As1, B1);                  // tile kt+1
      __syncthreads();
    }
  }

  // C/D layout: col = lane&15, row = quad*4 + reg
#pragma unroll
  for (int mi = 0; mi < 8; ++mi)
#pragma unroll
    for (int ni = 0; ni < 4; ++ni)
#pragma unroll
      for (int t = 0; t < 4; ++t)
        epi(b, ks, tm + moff + mi * 16 + quad * 4 + t, tn + noff + ni * 16 + fr, acc[mi][ni][t]);
}

// ---- reg-staged pipelined GEMM (kept for the COMB path, which must fold
// masked WpT into A during staging — global_load_lds can't transform data).
#define BM 128
#define BN 128
#define BK 32

template <int MW, bool COMB, typename Epi>
__global__ __launch_bounds__(256, MW) void gemm_pipe(
    const unsigned short* __restrict__ Ap, size_t sA,
    const unsigned short* __restrict__ WtP, const unsigned char* __restrict__ McP,
    const unsigned short* __restrict__ Bp, size_t sB,
    int swz, int ksN, int nit, Epi epi) {
  __shared__ __align__(16) unsigned short As[2 * BM * BK];
  __shared__ __align__(16) unsigned short Bs[2 * BN * BK];
  int bx = blockIdx.x, by = blockIdx.y, z = blockIdx.z;
  if (swz == 1) {
    int lin = bx + (by << 3);
    int r = lin & 7, s = lin >> 3;
    bx = ((r & 3) << 1) | (s & 1);
    by = ((r >> 2) << 2) | (s >> 1);
  } else if (swz == 2) {
    int lin = bx + (z << 3);
    int xcd = lin & 7, q = lin >> 3;
    z = (xcd << 3) + (q >> 3);
    bx = q & 7;
  }
  const int b = z / ksN, ks = z - b * ksN;
  const int kbase = ks * nit * BK;
  const int tm = bx * BM, tn = by * BN;
  const unsigned short* Ab = Ap + (size_t)b * sA;
  const unsigned short* Bb = Bp + (size_t)b * sB;
  const unsigned short* Wb = COMB ? (WtP + (size_t)b * sA) : nullptr;
  const int tid = threadIdx.x;
  const int w = tid >> 6, l = tid & 63;
  const int lr = l >> 2, lc = l & 3;
  const int fr = l & 15, quad = l >> 4;
  const int moff = (w & 1) * 64, noff = (w >> 1) * 64;
  const int r0 = w * 16 + lr, r1 = (w + 4) * 16 + lr;
  const int kc0 = lc ^ ((r0 >> 1) & 3), kc1 = lc ^ ((r1 >> 1) & 3);
  const size_t ao0 = (size_t)(tm + r0) * NN + kbase + kc0 * 8;
  const size_t ao1 = (size_t)(tm + r1) * NN + kbase + kc1 * 8;
  const size_t bo0 = (size_t)(tn + r0) * NN + kbase + kc0 * 8;
  const size_t bo1 = (size_t)(tn + r1) * NN + kbase + kc1 * 8;
  const int ls0 = r0 * BK + lc * 8, ls1 = r1 * BK + lc * 8;

  unsigned short* const As0 = As;           unsigned short* const As1 = As + BM * BK;
  unsigned short* const Bs0 = Bs;           unsigned short* const Bs1 = Bs + BN * BK;

  f32x4 acc[4][4];
#pragma unroll
  for (int mi = 0; mi < 4; ++mi)
#pragma unroll
    for (int ni = 0; ni < 4; ++ni) acc[mi][ni] = (f32x4){0.f, 0.f, 0.f, 0.f};

  struct RegSet {
    u16x8 a0, a1, b0, b1;
    u16x8 w0, w1;
    unsigned long long m0, m1;
  };
  RegSet R0, R1;

  auto load = [&](RegSet& R, int kt) {
    size_t kk = (size_t)kt * BK;
    R.a0 = *(const u16x8*)(Ab + ao0 + kk);
    R.a1 = *(const u16x8*)(Ab + ao1 + kk);
    R.b0 = *(const u16x8*)(Bb + bo0 + kk);
    R.b1 = *(const u16x8*)(Bb + bo1 + kk);
    if constexpr (COMB) {
      R.w0 = *(const u16x8*)(Wb + ao0 + kk);
      R.w1 = *(const u16x8*)(Wb + ao1 + kk);
      R.m0 = *(const unsigned long long*)(McP + ao0 + kk);
      R.m1 = *(const unsigned long long*)(McP + ao1 + kk);
    }
  };
  auto wr = [&](const RegSet& R, unsigned short* Ad, unsigned short* Bd) {
    if constexpr (COMB) {
      u16x8 f0, f1;
#pragma unroll
      for (int j = 0; j < 8; ++j) {
        float s0 = bf2f(R.a0[j]);
        if ((R.m0 >> (8 * j)) & 1ull) s0 += bf2f(R.w0[j]);
        f0[j] = f2bf(s0);
        float s1 = bf2f(R.a1[j]);
        if ((R.m1 >> (8 * j)) & 1ull) s1 += bf2f(R.w1[j]);
        f1[j] = f2bf(s1);
      }
      *(u16x8*)(Ad + ls0) = f0;
      *(u16x8*)(Ad + ls1) = f1;
    } else {
      *(u16x8*)(Ad + ls0) = R.a0;
      *(u16x8*)(Ad + ls1) = R.a1;
    }
    *(u16x8*)(Bd + ls0) = R.b0;
    *(u16x8*)(Bd + ls1) = R.b1;
  };
  auto compute = [&](const unsigned short* Ad, const unsigned short* Bd) {
    bf16x8 af[4], bfr[4];
#pragma unroll
    for (int mi = 0; mi < 4; ++mi) {
      int r = moff + mi * 16 + fr;
      int kc = quad ^ ((r >> 1) & 3);
      af[mi] = *(const bf16x8*)(Ad + r * BK + kc * 8);
    }
#pragma unroll
    for (int ni = 0; ni < 4; ++ni) {
      int r = noff + ni * 16 + fr;
      int kc = quad ^ ((r >> 1) & 3);
      bfr[ni] = *(const bf16x8*)(Bd + r * BK + kc * 8);
    }
#pragma unroll
    for (int mi = 0; mi < 4; ++mi)
#pragma unroll
      for (int ni = 0; ni < 4; ++ni)
        acc[mi][ni] = __builtin_amdgcn_mfma_f32_16x16x32_bf16(af[mi], bfr[ni], acc[mi][ni], 0, 0, 0);
  };

  load(R0, 0);
  load(R1, 1);
  wr(R0, As0, Bs0);
  load(R0, 2);
  LGKM_BARRIER();
#pragma unroll 1
  for (int kt = 0; kt < nit - 2; kt += 2) {
    compute(As0, Bs0);
    wr(R1, As1, Bs1);
    if (kt + 3 < nit) load(R1, kt + 3);
    LGKM_BARRIER();
    compute(As1, Bs1);
    wr(R0, As0, Bs0);
    if (kt + 4 < nit) load(R0, kt + 4);
    LGKM_BARRIER();
  }
  compute(As0, Bs0);
  wr(R1, As1, Bs1);
  LGKM_BARRIER();
  compute(As1, Bs1);

#pragma unroll
  for (int mi = 0; mi < 4; ++mi)
#pragma unroll
    for (int ni = 0; ni < 4; ++ni)
#pragma unroll
      for (int t = 0; t < 4; ++t)
        epi(b, ks, tm + moff + mi * 16 + quad * 4 + t, tn + noff + ni * 16 + fr, acc[mi][ni][t]);
}

// ---------------- gated hop-2 sparse fixup (expected: nnz==0, exits) ----------------
__global__ __launch_bounds__(256) void hop2_fix(const unsigned short* __restrict__ Wp,
    const unsigned short* __restrict__ WpT, const int* __restrict__ nnz,
    const unsigned int* __restrict__ entries, unsigned short* __restrict__ WcombT) {
  int n = *nnz;
  if (n > CAP) n = CAP;
  if (n == 0) return;
  __shared__ float rbuf[256];
  const int b = blockIdx.x;
  const size_t bnn = (size_t)b * NNNN;
  for (int e = blockIdx.y; e < n; e += gridDim.y) {
    unsigned int ent = entries[e];
    int j = ent >> 16, i = ent & 0xFFFF;
    float s = 0.f;
    for (int k = threadIdx.x; k < NN; k += 256) {
      float u = 0.f, v = 0.f;
      const unsigned short* wj  = Wp  + bnn + (size_t)j * NN;
      const unsigned short* wtk = WpT + bnn + (size_t)k * NN;
      const unsigned short* wk  = Wp  + bnn + (size_t)k * NN;
      const unsigned short* wti = WpT + bnn + (size_t)i * NN;
      for (int t = 0; t < NN; ++t) {
        u += bf2f(wj[t]) * bf2f(wtk[t]);
        v += bf2f(wk[t]) * bf2f(wti[t]);
      }
      s += u * v;
    }
    rbuf[threadIdx.x] = s;
    __syncthreads();
    for (int off = 128; off > 0; off >>= 1) {
      if (threadIdx.x < off) rbuf[threadIdx.x] += rbuf[threadIdx.x + off];
      __syncthreads();
    }
    if (threadIdx.x == 0) {
      size_t idx = bnn + (size_t)i * NN + j;
      WcombT[idx] = f2bf(bf2f(WcombT[idx]) + rbuf[0]);
    }
    __syncthreads();
  }
}

// ---------------- fused (sum 2 agg partials) + Linear + residual + LayerNorm ----------------
#define FROWS 16
__global__ __launch_bounds__(256) void fused_out(const float* __restrict__ a0p,
    const float* __restrict__ a1p, const float* __restrict__ x,
    const float* __restrict__ W, const float* __restrict__ bias,
    const float* __restrict__ g2, const float* __restrict__ bsh,
    float* __restrict__ out) {
  __shared__ unsigned short Wl[128 * 136];
  __shared__ float ar[256];
  __shared__ float wred[8];
  const int tid = threadIdx.x;
  for (int e = tid; e < 16384; e += 256) Wl[(e >> 7) * 136 + (e & 127)] = f2bf(W[e]);
  const int half = tid >> 7, o = tid & 127;
  const int w = tid >> 6, lane = tid & 63;
  const float bo = bias[o], go = g2[o], b2o = bsh[o];
  const size_t row0 = (size_t)blockIdx.x * FROWS;
  size_t rb = row0 * DD;
  float av = a0p[rb + tid] + a1p[rb + tid];
  float xv = x[rb + tid];
  __syncthreads();  // Wl ready
  for (int rr = 0; rr < FROWS; rr += 2) {
    ar[tid] = av;
    const float xcur = xv;
    const size_t rbc = (row0 + rr) * DD;
    __syncthreads();  // ar ready
    if (rr + 2 < FROWS) {
      size_t rb2 = (row0 + rr + 2) * DD;
      av = a0p[rb2 + tid] + a1p[rb2 + tid];
      xv = x[rb2 + tid];
    }
    float hv = bo + xcur;
    const unsigned short* wrow = &Wl[o * 136];
    const float* arow = &ar[half * 128];
#pragma unroll
    for (int d8 = 0; d8 < 16; ++d8) {
      bf16x8 wv = *(const bf16x8*)(wrow + d8 * 8);
#pragma unroll
      for (int t = 0; t < 8; ++t) hv += (float)wv[t] * arow[d8 * 8 + t];
    }
    float s = hv, q = hv * hv;
#pragma unroll
    for (int off = 32; off > 0; off >>= 1) {
      s += __shfl_xor(s, off);
      q += __shfl_xor(q, off);
    }
    if (lane == 0) { wred[w] = s; wred[4 + w] = q; }
    __syncthreads();  // wred ready (also gates ar overwrite next iter)
    float st = wred[half * 2] + wred[half * 2 + 1];
    float qt = wred[4 + half * 2] + wred[4 + half * 2 + 1];
    float mean = st * (1.0f / 128.0f);
    float var = (qt - 128.0f * mean * mean) * (1.0f / 127.0f);
    var = fmaxf(var, 0.0f);
    float stdv = sqrtf(var);
    out[rbc + tid] = go * (hv - mean) / (stdv + EPSF) + b2o;
  }
}

// ---------------- launch ----------------
extern "C" void kernel_launch(void* const* d_in, const int* in_sizes, int n_in,
                              void* d_out, int out_size, void* d_ws, size_t ws_size,
                              hipStream_t stream) {
  (void)in_sizes; (void)n_in; (void)out_size; (void)ws_size;
  const float* x    = (const float*)d_in[0];
  const float* adjw = (const float*)d_in[1];
  const float* adj  = (const float*)d_in[2];
  const float* W    = (const float*)d_in[3];
  const float* bias = (const float*)d_in[4];
  const float* a2   = (const float*)d_in[5];
  const float* b2   = (const float*)d_in[6];
  float* out = (float*)d_out;

  char* ws = (char*)d_ws;
  const size_t MB = 1048576;
  unsigned short* Wp_bf   = (unsigned short*)(ws);             // 64 MB
  unsigned short* WpT_bf  = (unsigned short*)(ws + 64 * MB);   // 64 MB
  unsigned short* WcombT  = (unsigned short*)(ws + 128 * MB);  // 64 MB
  unsigned short* xT_bf   = (unsigned short*)(ws + 192 * MB);  // 8 MB
  unsigned short* adj_bf  = (unsigned short*)(ws + 200 * MB);  // 2 MB
  unsigned short* adjT_bf = (unsigned short*)(ws + 202 * MB);  // 2 MB
  unsigned short* A2_bf   = (unsigned short*)(ws + 204 * MB);  // 2 MB
  unsigned short* A2T_bf  = (unsigned short*)(ws + 206 * MB);  // 2 MB
  float* sqpart           = (float*)(ws + 208 * MB);           // 16 MB (4 partials)
  float* agg1             = (float*)(ws + 200 * MB);           // 16 MB (overlaps consumed bufs)
  unsigned char* mcode    = (unsigned char*)(ws + 224 * MB);   // 1 MB
  unsigned int* entries   = (unsigned int*)(ws + 225 * MB);    // 64 KB
  int* nnz2               = (int*)(ws + 226 * MB);             // 4 B
  float* agg0 = out;  // d_out doubles as agg partial 0

  hipMemsetAsync(nnz2, 0, 4, stream);

  dim3 blk32(32, 8, 1);
  convert_wp<<<dim3(16, 16, 32), 256, 0, stream>>>(adjw, Wp_bf, WpT_bf);
  convert_x<<<dim3(4, 32, 32), blk32, 0, stream>>>(x, xT_bf);
  mask0cvt<<<dim3(32, 32, 1), blk32, 0, stream>>>(adj, mcode, adj_bf, adjT_bf);

  // A^2: K-split 4, exact integer partials, plain stores
  gemm_big<2><<<dim3(4, 8, 4), 256, 0, stream>>>(
      adj_bf, (size_t)0, adjT_bf, (size_t)0, 0, 4, 8, EpiSqPart{sqpart});
  scan_a2<<<dim3(32, 32, 1), blk32, 0, stream>>>(sqpart, A2_bf, A2T_bf, mcode);
  // A^4: K-split 4 (A^2 ints < 256 exact in bf16)
  gemm_big<2><<<dim3(4, 8, 4), 256, 0, stream>>>(
      A2_bf, (size_t)0, A2T_bf, (size_t)0, 0, 4, 8, EpiSqPart{sqpart});
  scan_a4<<<dim3(4096, 1, 1), 256, 0, stream>>>(sqpart, entries, nnz2);

  // big batched gemm: WcombT = mask2 .* (Wp^2)^T  (batch->XCD swizzle)
  gemm_big<2><<<dim3(4, 8, 32), 256, 0, stream>>>(
      WpT_bf, NNNN, Wp_bf, NNNN, 2, 1, NN / GBK, EpiWcomb{mcode, WcombT});

  hop2_fix<<<dim3(32, 8, 1), 256, 0, stream>>>(Wp_bf, WpT_bf, nnz2, entries, WcombT);

  // agg = (WcombT + mask1^T.*WpT) @ x — K-split 2 partials (batch->XCD swizzle)
  gemm_pipe<2, true><<<dim3(8, 1, 64), 256, 0, stream>>>(
      WcombT, NNNN, WpT_bf, mcode, xT_bf, (size_t)DD * NN, 2, 2, 16,
      EpiAggPart{agg0, agg1});

  fused_out<<<dim3(2048, 1, 1), 256, 0, stream>>>(agg0, agg1, x, W, bias, a2, b2, out);
}

// Round 5
// 477.646 us; speedup vs baseline: 1.0933x; 1.0933x over previous
//
#include <hip/hip_runtime.h>

#define NN 1024
#define BB 32
#define DD 128
#define EPSF 1e-6f
#define CAP 16384
#define NNNN ((size_t)NN * NN)

typedef __bf16 bf16x8 __attribute__((ext_vector_type(8)));
typedef float  f32x4  __attribute__((ext_vector_type(4)));
typedef unsigned short u16x8 __attribute__((ext_vector_type(8)));

typedef __attribute__((address_space(3))) unsigned int lds_u32;
typedef __attribute__((address_space(1))) const unsigned int glb_u32;

__device__ __forceinline__ lds_u32* lds_cast(const void* p) {
  return (lds_u32*)(unsigned int)(unsigned long long)p;
}
__device__ __forceinline__ glb_u32* glb_cast(const void* p) {
  return (glb_u32*)(unsigned long long)p;
}

__device__ __forceinline__ float bf2f(unsigned short u) {
  union { unsigned int i; float f; } v; v.i = ((unsigned int)u) << 16; return v.f;
}
__device__ __forceinline__ unsigned short f2bf(float f) {
  union { float f; unsigned int i; } v; v.f = f;
  unsigned int r = v.i + 0x7fffu + ((v.i >> 16) & 1u);
  return (unsigned short)(r >> 16);
}

// ---------------- convert / transpose kernels ----------------

__global__ __launch_bounds__(256) void convert_wp(const float* __restrict__ src,
    unsigned short* __restrict__ Wp, unsigned short* __restrict__ WpT) {
  __shared__ float tile[64][65];
  const int b = blockIdx.z;
  const int c0 = blockIdx.x * 64, r0 = blockIdx.y * 64;
  const int t = threadIdx.x;
  const int rr = t >> 3, cb = (t & 7) * 8;
  const size_t base = (size_t)b * NNNN;
#pragma unroll
  for (int p = 0; p < 2; ++p) {
    const int r = rr + p * 32;
    const float* srow = src + base + (size_t)(r0 + r) * NN + c0 + cb;
    f32x4 v0 = *(const f32x4*)srow;
    f32x4 v1 = *(const f32x4*)(srow + 4);
    u16x8 w;
#pragma unroll
    for (int j = 0; j < 4; ++j) { w[j] = f2bf(v0[j]); w[4 + j] = f2bf(v1[j]); }
    *(u16x8*)(Wp + base + (size_t)(r0 + r) * NN + c0 + cb) = w;
#pragma unroll
    for (int j = 0; j < 4; ++j) { tile[r][cb + j] = v0[j]; tile[r][cb + 4 + j] = v1[j]; }
  }
  __syncthreads();
#pragma unroll
  for (int p = 0; p < 2; ++p) {
    const int r = rr + p * 32;
    u16x8 w;
#pragma unroll
    for (int j = 0; j < 8; ++j) w[j] = f2bf(tile[cb + j][r]);
    *(u16x8*)(WpT + base + (size_t)(c0 + r) * NN + r0 + cb) = w;
  }
}

__global__ __launch_bounds__(256) void convert_x(const float* __restrict__ x,
    unsigned short* __restrict__ xT) {
  __shared__ float tile[32][33];
  const int b = blockIdx.z;
  const int d0 = blockIdx.x * 32, n0 = blockIdx.y * 32;
  const int tx = threadIdx.x, ty = threadIdx.y;
#pragma unroll
  for (int s = 0; s < 4; ++s) {
    int rr = ty + s * 8;
    tile[rr][tx] = x[(size_t)b * NN * DD + (size_t)(n0 + rr) * DD + d0 + tx];
  }
  __syncthreads();
#pragma unroll
  for (int s = 0; s < 4; ++s) {
    int rr = ty + s * 8;
    xT[(size_t)b * DD * NN + (size_t)(d0 + rr) * NN + n0 + tx] = f2bf(tile[tx][rr]);
  }
}

// adj -> mcode bit0 (= adj[j,i]==1 at [i,j]), adj_bf, adjT_bf
__global__ __launch_bounds__(256) void mask0cvt(const float* __restrict__ adj,
    unsigned char* __restrict__ mcode, unsigned short* __restrict__ adjbf,
    unsigned short* __restrict__ adjTbf) {
  __shared__ float tile[32][33];
  const int i0 = blockIdx.x * 32, j0 = blockIdx.y * 32;
  const int tx = threadIdx.x, ty = threadIdx.y;
#pragma unroll
  for (int s = 0; s < 4; ++s) {
    int rr = ty + s * 8;
    float v = adj[(size_t)(j0 + rr) * NN + i0 + tx];
    adjbf[(size_t)(j0 + rr) * NN + i0 + tx] = f2bf(v);
    tile[rr][tx] = v;
  }
  __syncthreads();
#pragma unroll
  for (int s = 0; s < 4; ++s) {
    int rr = ty + s * 8;
    float v = tile[tx][rr];
    adjTbf[(size_t)(i0 + rr) * NN + j0 + tx] = f2bf(v);
    mcode[(size_t)(i0 + rr) * NN + j0 + tx] = (v == 1.0f) ? 1 : 0;
  }
}

// sum 4 K-split partials (exact ints) -> A2 bf16, A2T bf16, mcode bit1 where ==1
__global__ __launch_bounds__(256) void scan_a2(const float* __restrict__ P,
    unsigned short* __restrict__ A2, unsigned short* __restrict__ A2T,
    unsigned char* __restrict__ mcode) {
  __shared__ float tile[32][33];
  const int m0 = blockIdx.x * 32, n0 = blockIdx.y * 32;
  const int tx = threadIdx.x, ty = threadIdx.y;
#pragma unroll
  for (int s = 0; s < 4; ++s) {
    int rr = ty + s * 8;
    size_t idx = (size_t)(m0 + rr) * NN + n0 + tx;
    float v = P[idx] + P[NNNN + idx] + P[2 * NNNN + idx] + P[3 * NNNN + idx];
    A2[idx] = f2bf(v);
    tile[rr][tx] = v;
  }
  __syncthreads();
#pragma unroll
  for (int s = 0; s < 4; ++s) {
    int rr = ty + s * 8;
    float v = tile[tx][rr];
    A2T[(size_t)(n0 + rr) * NN + m0 + tx] = f2bf(v);
    if (v == 1.0f) mcode[(size_t)(n0 + rr) * NN + m0 + tx] |= 2;
  }
}

// sum 4 partials of A^4; record entries (m<<16)|n where ==1.0
__global__ __launch_bounds__(256) void scan_a4(const float* __restrict__ P,
    unsigned int* __restrict__ entries, int* __restrict__ nnz) {
  size_t e = (size_t)blockIdx.x * 256 + threadIdx.x;
  float v = P[e] + P[NNNN + e] + P[2 * NNNN + e] + P[3 * NNNN + e];
  if (v == 1.0f) {
    int idx = atomicAdd(nnz, 1);
    if (idx < CAP) entries[idx] = ((unsigned)(e >> 10) << 16) | (unsigned)(e & 1023);
  }
}

// ---------------- MFMA GEMM tiles ----------------
// C[m,n] = sum_k A[m,k]*B[n,k].
#define BM 128
#define BN 128
#define BK 32

struct EpiWcomb {  // mask2-gated bf16 write
  const unsigned char* mc;
  unsigned short* out;
  __device__ __forceinline__ void operator()(int b, int ks, int i, int j, float v) const {
    size_t idx = (size_t)i * NN + j;
    out[(size_t)b * NNNN + idx] = (mc[idx] & 2) ? f2bf(v) : (unsigned short)0;
  }
};

struct EpiSqPart {  // K-split partial, plain store
  float* buf;
  __device__ __forceinline__ void operator()(int b, int ks, int i, int j, float v) const {
    buf[(size_t)ks * NNNN + (size_t)i * NN + j] = v;
  }
};

struct EpiAggPart {  // 2-way K-split partials (p0 = d_out, p1 = ws)
  float* p0;
  float* p1;
  __device__ __forceinline__ void operator()(int b, int ks, int i, int d, float v) const {
    (ks ? p1 : p0)[(size_t)b * NN * DD + (size_t)i * DD + d] = v;
  }
};

#define LGKM_BARRIER() do { \
  asm volatile("s_waitcnt lgkmcnt(0)" ::: "memory"); \
  __builtin_amdgcn_s_barrier(); \
  asm volatile("" ::: "memory"); } while (0)

// ---- triple-buffered counted-vmcnt GEMM (T4: never drain vmcnt to 0 in the
// main loop). MFMA-busy is only ~28us across all prior structures; the rest
// was exposed DMA latency — __syncthreads drains the just-issued prefetch at
// every K-step. Here tile kt's DMA is issued at iteration kt-2 and waited with
// s_waitcnt vmcnt(4) (tile kt+1 stays in flight), giving ~2 K-windows of
// latency cover. ONE raw barrier per K-step, placed so it orders
// {all waves finished compute(kt-1)} before {stage overwrites that slot}.
// Hang audit: uniform barrier counts across all waves; per-wave vmcnt FIFO
// accounting is consistent (4 loads/stage, epilogue drains to 0).
template <int MW, typename Epi>
__global__ __launch_bounds__(256, MW) void gemm_lds(
    const unsigned short* __restrict__ Ap, size_t sA,
    const unsigned short* __restrict__ Bp, size_t sB,
    int swz, int ksN, int nit, Epi epi) {
  __shared__ __align__(16) unsigned short As[3 * BM * BK];  // 24 KB
  __shared__ __align__(16) unsigned short Bs[3 * BN * BK];  // 24 KB
  int bx = blockIdx.x, by = blockIdx.y, z = blockIdx.z;
  if (swz == 1) {  // 2x4 rect for per-XCD L2 locality
    int lin = bx + (by << 3);
    int r = lin & 7, s = lin >> 3;
    bx = ((r & 3) << 1) | (s & 1);
    by = ((r >> 2) << 2) | (s >> 1);
  } else if (swz == 2) {  // batch->XCD co-location; grid (8,8,Z), Z%8==0
    int lin = bx + (by << 3) + (z << 6);
    int xcd = lin & 7, q = lin >> 3;
    z = xcd + ((q >> 6) << 3);
    int tile = q & 63;
    bx = tile & 7; by = tile >> 3;
  }
  const int b = z / ksN, ks = z - b * ksN;
  const int kbase = ks * nit * BK;
  const int tm = bx * BM, tn = by * BN;
  const unsigned short* Ab = Ap + (size_t)b * sA;
  const unsigned short* Bb = Bp + (size_t)b * sB;
  const int tid = threadIdx.x;
  const int w = tid >> 6, l = tid & 63;
  const int fr = l & 15, quad = l >> 4;
  const int moff = (w & 1) * 64, noff = (w >> 1) * 64;

  // staging geometry: each wave DMAs 2 chunks of 16 rows (1024B each) per
  // operand. LDS dest linear (wave-uniform base + lane*16); global source
  // pre-swizzled (m173) so compute()'s XOR-swizzled ds_read sees the right data.
  const int sr = l >> 2, ss = l & 3;
  const int r0 = w * 16 + sr;
  const int r1 = 64 + w * 16 + sr;
  const int kc0 = ss ^ ((r0 >> 1) & 3);
  const int kc1 = ss ^ ((r1 >> 1) & 3);
  const unsigned short* gA0 = Ab + (size_t)(tm + r0) * NN + kbase + kc0 * 8;
  const unsigned short* gA1 = Ab + (size_t)(tm + r1) * NN + kbase + kc1 * 8;
  const unsigned short* gB0 = Bb + (size_t)(tn + r0) * NN + kbase + kc0 * 8;
  const unsigned short* gB1 = Bb + (size_t)(tn + r1) * NN + kbase + kc1 * 8;

  f32x4 acc[4][4];
#pragma unroll
  for (int mi = 0; mi < 4; ++mi)
#pragma unroll
    for (int ni = 0; ni < 4; ++ni) acc[mi][ni] = (f32x4){0.f, 0.f, 0.f, 0.f};

  auto stage = [&](int off, int kt) {  // off in shorts, same for As/Bs slots
    const size_t kk = (size_t)kt * BK;
    __builtin_amdgcn_global_load_lds(glb_cast(gA0 + kk),
        lds_cast(As + off + (w * 16) * BK), 16, 0, 0);
    __builtin_amdgcn_global_load_lds(glb_cast(gA1 + kk),
        lds_cast(As + off + (64 + w * 16) * BK), 16, 0, 0);
    __builtin_amdgcn_global_load_lds(glb_cast(gB0 + kk),
        lds_cast(Bs + off + (w * 16) * BK), 16, 0, 0);
    __builtin_amdgcn_global_load_lds(glb_cast(gB1 + kk),
        lds_cast(Bs + off + (64 + w * 16) * BK), 16, 0, 0);
  };
  auto compute = [&](const unsigned short* Ad, const unsigned short* Bd) {
    bf16x8 af[4], bfr[4];
#pragma unroll
    for (int mi = 0; mi < 4; ++mi) {
      int r = moff + mi * 16 + fr;
      int kc = quad ^ ((r >> 1) & 3);
      af[mi] = *(const bf16x8*)(Ad + r * BK + kc * 8);
    }
#pragma unroll
    for (int ni = 0; ni < 4; ++ni) {
      int r = noff + ni * 16 + fr;
      int kc = quad ^ ((r >> 1) & 3);
      bfr[ni] = *(const bf16x8*)(Bd + r * BK + kc * 8);
    }
#pragma unroll
    for (int mi = 0; mi < 4; ++mi)
#pragma unroll
      for (int ni = 0; ni < 4; ++ni)
        acc[mi][ni] = __builtin_amdgcn_mfma_f32_16x16x32_bf16(af[mi], bfr[ni], acc[mi][ni], 0, 0, 0);
  };

  // prologue: tiles 0,1 in flight
  stage(0, 0);
  stage(BM * BK, 1);
  int o0 = 0, o1 = BM * BK, o2 = 2 * BM * BK;
#pragma unroll 1
  for (int kt = 0; kt < nit; ++kt) {
    if (kt + 1 < nit) {
      asm volatile("s_waitcnt vmcnt(4)" ::: "memory");  // tile kt landed; kt+1 in flight
    } else {
      asm volatile("s_waitcnt vmcnt(0)" ::: "memory");  // final tile
    }
    __builtin_amdgcn_sched_barrier(0);
    __builtin_amdgcn_s_barrier();
    // all waves: past compute(kt-1) (program order) and tile kt visible.
    if (kt + 2 < nit) stage(o2, kt + 2);   // overwrites slot computed at kt-1
    compute(As + o0, Bs + o0);             // tile kt
    int t = o0; o0 = o1; o1 = o2; o2 = t;
  }

  // C/D layout: col = lane&15, row = quad*4 + reg
#pragma unroll
  for (int mi = 0; mi < 4; ++mi)
#pragma unroll
    for (int ni = 0; ni < 4; ++ni)
#pragma unroll
      for (int t = 0; t < 4; ++t)
        epi(b, ks, tm + moff + mi * 16 + quad * 4 + t, tn + noff + ni * 16 + fr, acc[mi][ni][t]);
}

// ---- reg-staged pipelined GEMM (kept for the COMB path, which must fold
// masked WpT into A during staging — global_load_lds can't transform data).
template <int MW, bool COMB, typename Epi>
__global__ __launch_bounds__(256, MW) void gemm_pipe(
    const unsigned short* __restrict__ Ap, size_t sA,
    const unsigned short* __restrict__ WtP, const unsigned char* __restrict__ McP,
    const unsigned short* __restrict__ Bp, size_t sB,
    int swz, int ksN, int nit, Epi epi) {
  __shared__ __align__(16) unsigned short As[2 * BM * BK];
  __shared__ __align__(16) unsigned short Bs[2 * BN * BK];
  int bx = blockIdx.x, by = blockIdx.y, z = blockIdx.z;
  if (swz == 1) {
    int lin = bx + (by << 3);
    int r = lin & 7, s = lin >> 3;
    bx = ((r & 3) << 1) | (s & 1);
    by = ((r >> 2) << 2) | (s >> 1);
  } else if (swz == 2) {
    int lin = bx + (z << 3);
    int xcd = lin & 7, q = lin >> 3;
    z = (xcd << 3) + (q >> 3);
    bx = q & 7;
  }
  const int b = z / ksN, ks = z - b * ksN;
  const int kbase = ks * nit * BK;
  const int tm = bx * BM, tn = by * BN;
  const unsigned short* Ab = Ap + (size_t)b * sA;
  const unsigned short* Bb = Bp + (size_t)b * sB;
  const unsigned short* Wb = COMB ? (WtP + (size_t)b * sA) : nullptr;
  const int tid = threadIdx.x;
  const int w = tid >> 6, l = tid & 63;
  const int lr = l >> 2, lc = l & 3;
  const int fr = l & 15, quad = l >> 4;
  const int moff = (w & 1) * 64, noff = (w >> 1) * 64;
  const int r0 = w * 16 + lr, r1 = (w + 4) * 16 + lr;
  const int kc0 = lc ^ ((r0 >> 1) & 3), kc1 = lc ^ ((r1 >> 1) & 3);
  const size_t ao0 = (size_t)(tm + r0) * NN + kbase + kc0 * 8;
  const size_t ao1 = (size_t)(tm + r1) * NN + kbase + kc1 * 8;
  const size_t bo0 = (size_t)(tn + r0) * NN + kbase + kc0 * 8;
  const size_t bo1 = (size_t)(tn + r1) * NN + kbase + kc1 * 8;
  const int ls0 = r0 * BK + lc * 8, ls1 = r1 * BK + lc * 8;

  unsigned short* const As0 = As;           unsigned short* const As1 = As + BM * BK;
  unsigned short* const Bs0 = Bs;           unsigned short* const Bs1 = Bs + BN * BK;

  f32x4 acc[4][4];
#pragma unroll
  for (int mi = 0; mi < 4; ++mi)
#pragma unroll
    for (int ni = 0; ni < 4; ++ni) acc[mi][ni] = (f32x4){0.f, 0.f, 0.f, 0.f};

  struct RegSet {
    u16x8 a0, a1, b0, b1;
    u16x8 w0, w1;
    unsigned long long m0, m1;
  };
  RegSet R0, R1;

  auto load = [&](RegSet& R, int kt) {
    size_t kk = (size_t)kt * BK;
    R.a0 = *(const u16x8*)(Ab + ao0 + kk);
    R.a1 = *(const u16x8*)(Ab + ao1 + kk);
    R.b0 = *(const u16x8*)(Bb + bo0 + kk);
    R.b1 = *(const u16x8*)(Bb + bo1 + kk);
    if constexpr (COMB) {
      R.w0 = *(const u16x8*)(Wb + ao0 + kk);
      R.w1 = *(const u16x8*)(Wb + ao1 + kk);
      R.m0 = *(const unsigned long long*)(McP + ao0 + kk);
      R.m1 = *(const unsigned long long*)(McP + ao1 + kk);
    }
  };
  auto wr = [&](const RegSet& R, unsigned short* Ad, unsigned short* Bd) {
    if constexpr (COMB) {
      u16x8 f0, f1;
#pragma unroll
      for (int j = 0; j < 8; ++j) {
        float s0 = bf2f(R.a0[j]);
        if ((R.m0 >> (8 * j)) & 1ull) s0 += bf2f(R.w0[j]);
        f0[j] = f2bf(s0);
        float s1 = bf2f(R.a1[j]);
        if ((R.m1 >> (8 * j)) & 1ull) s1 += bf2f(R.w1[j]);
        f1[j] = f2bf(s1);
      }
      *(u16x8*)(Ad + ls0) = f0;
      *(u16x8*)(Ad + ls1) = f1;
    } else {
      *(u16x8*)(Ad + ls0) = R.a0;
      *(u16x8*)(Ad + ls1) = R.a1;
    }
    *(u16x8*)(Bd + ls0) = R.b0;
    *(u16x8*)(Bd + ls1) = R.b1;
  };
  auto compute = [&](const unsigned short* Ad, const unsigned short* Bd) {
    bf16x8 af[4], bfr[4];
#pragma unroll
    for (int mi = 0; mi < 4; ++mi) {
      int r = moff + mi * 16 + fr;
      int kc = quad ^ ((r >> 1) & 3);
      af[mi] = *(const bf16x8*)(Ad + r * BK + kc * 8);
    }
#pragma unroll
    for (int ni = 0; ni < 4; ++ni) {
      int r = noff + ni * 16 + fr;
      int kc = quad ^ ((r >> 1) & 3);
      bfr[ni] = *(const bf16x8*)(Bd + r * BK + kc * 8);
    }
#pragma unroll
    for (int mi = 0; mi < 4; ++mi)
#pragma unroll
      for (int ni = 0; ni < 4; ++ni)
        acc[mi][ni] = __builtin_amdgcn_mfma_f32_16x16x32_bf16(af[mi], bfr[ni], acc[mi][ni], 0, 0, 0);
  };

  load(R0, 0);
  load(R1, 1);
  wr(R0, As0, Bs0);
  load(R0, 2);
  LGKM_BARRIER();
#pragma unroll 1
  for (int kt = 0; kt < nit - 2; kt += 2) {
    compute(As0, Bs0);
    wr(R1, As1, Bs1);
    if (kt + 3 < nit) load(R1, kt + 3);
    LGKM_BARRIER();
    compute(As1, Bs1);
    wr(R0, As0, Bs0);
    if (kt + 4 < nit) load(R0, kt + 4);
    LGKM_BARRIER();
  }
  compute(As0, Bs0);
  wr(R1, As1, Bs1);
  LGKM_BARRIER();
  compute(As1, Bs1);

#pragma unroll
  for (int mi = 0; mi < 4; ++mi)
#pragma unroll
    for (int ni = 0; ni < 4; ++ni)
#pragma unroll
      for (int t = 0; t < 4; ++t)
        epi(b, ks, tm + moff + mi * 16 + quad * 4 + t, tn + noff + ni * 16 + fr, acc[mi][ni][t]);
}

// ---------------- gated hop-2 sparse fixup (expected: nnz==0, exits) ----------------
__global__ __launch_bounds__(256) void hop2_fix(const unsigned short* __restrict__ Wp,
    const unsigned short* __restrict__ WpT, const int* __restrict__ nnz,
    const unsigned int* __restrict__ entries, unsigned short* __restrict__ WcombT) {
  int n = *nnz;
  if (n > CAP) n = CAP;
  if (n == 0) return;
  __shared__ float rbuf[256];
  const int b = blockIdx.x;
  const size_t bnn = (size_t)b * NNNN;
  for (int e = blockIdx.y; e < n; e += gridDim.y) {
    unsigned int ent = entries[e];
    int j = ent >> 16, i = ent & 0xFFFF;
    float s = 0.f;
    for (int k = threadIdx.x; k < NN; k += 256) {
      float u = 0.f, v = 0.f;
      const unsigned short* wj  = Wp  + bnn + (size_t)j * NN;
      const unsigned short* wtk = WpT + bnn + (size_t)k * NN;
      const unsigned short* wk  = Wp  + bnn + (size_t)k * NN;
      const unsigned short* wti = WpT + bnn + (size_t)i * NN;
      for (int t = 0; t < NN; ++t) {
        u += bf2f(wj[t]) * bf2f(wtk[t]);
        v += bf2f(wk[t]) * bf2f(wti[t]);
      }
      s += u * v;
    }
    rbuf[threadIdx.x] = s;
    __syncthreads();
    for (int off = 128; off > 0; off >>= 1) {
      if (threadIdx.x < off) rbuf[threadIdx.x] += rbuf[threadIdx.x + off];
      __syncthreads();
    }
    if (threadIdx.x == 0) {
      size_t idx = bnn + (size_t)i * NN + j;
      WcombT[idx] = f2bf(bf2f(WcombT[idx]) + rbuf[0]);
    }
    __syncthreads();
  }
}

// ---------------- fused (sum 2 agg partials) + Linear + residual + LayerNorm ----------------
#define FROWS 16
__global__ __launch_bounds__(256) void fused_out(const float* __restrict__ a0p,
    const float* __restrict__ a1p, const float* __restrict__ x,
    const float* __restrict__ W, const float* __restrict__ bias,
    const float* __restrict__ g2, const float* __restrict__ bsh,
    float* __restrict__ out) {
  __shared__ unsigned short Wl[128 * 136];
  __shared__ float ar[256];
  __shared__ float wred[8];
  const int tid = threadIdx.x;
  for (int e = tid; e < 16384; e += 256) Wl[(e >> 7) * 136 + (e & 127)] = f2bf(W[e]);
  const int half = tid >> 7, o = tid & 127;
  const int w = tid >> 6, lane = tid & 63;
  const float bo = bias[o], go = g2[o], b2o = bsh[o];
  const size_t row0 = (size_t)blockIdx.x * FROWS;
  size_t rb = row0 * DD;
  float av = a0p[rb + tid] + a1p[rb + tid];
  float xv = x[rb + tid];
  __syncthreads();  // Wl ready
  for (int rr = 0; rr < FROWS; rr += 2) {
    ar[tid] = av;
    const float xcur = xv;
    const size_t rbc = (row0 + rr) * DD;
    __syncthreads();  // ar ready
    if (rr + 2 < FROWS) {
      size_t rb2 = (row0 + rr + 2) * DD;
      av = a0p[rb2 + tid] + a1p[rb2 + tid];
      xv = x[rb2 + tid];
    }
    float hv = bo + xcur;
    const unsigned short* wrow = &Wl[o * 136];
    const float* arow = &ar[half * 128];
#pragma unroll
    for (int d8 = 0; d8 < 16; ++d8) {
      bf16x8 wv = *(const bf16x8*)(wrow + d8 * 8);
#pragma unroll
      for (int t = 0; t < 8; ++t) hv += (float)wv[t] * arow[d8 * 8 + t];
    }
    float s = hv, q = hv * hv;
#pragma unroll
    for (int off = 32; off > 0; off >>= 1) {
      s += __shfl_xor(s, off);
      q += __shfl_xor(q, off);
    }
    if (lane == 0) { wred[w] = s; wred[4 + w] = q; }
    __syncthreads();  // wred ready (also gates ar overwrite next iter)
    float st = wred[half * 2] + wred[half * 2 + 1];
    float qt = wred[4 + half * 2] + wred[4 + half * 2 + 1];
    float mean = st * (1.0f / 128.0f);
    float var = (qt - 128.0f * mean * mean) * (1.0f / 127.0f);
    var = fmaxf(var, 0.0f);
    float stdv = sqrtf(var);
    out[rbc + tid] = go * (hv - mean) / (stdv + EPSF) + b2o;
  }
}

// ---------------- launch ----------------
extern "C" void kernel_launch(void* const* d_in, const int* in_sizes, int n_in,
                              void* d_out, int out_size, void* d_ws, size_t ws_size,
                              hipStream_t stream) {
  (void)in_sizes; (void)n_in; (void)out_size; (void)ws_size;
  const float* x    = (const float*)d_in[0];
  const float* adjw = (const float*)d_in[1];
  const float* adj  = (const float*)d_in[2];
  const float* W    = (const float*)d_in[3];
  const float* bias = (const float*)d_in[4];
  const float* a2   = (const float*)d_in[5];
  const float* b2   = (const float*)d_in[6];
  float* out = (float*)d_out;

  char* ws = (char*)d_ws;
  const size_t MB = 1048576;
  unsigned short* Wp_bf   = (unsigned short*)(ws);             // 64 MB
  unsigned short* WpT_bf  = (unsigned short*)(ws + 64 * MB);   // 64 MB
  unsigned short* WcombT  = (unsigned short*)(ws + 128 * MB);  // 64 MB
  unsigned short* xT_bf   = (unsigned short*)(ws + 192 * MB);  // 8 MB
  unsigned short* adj_bf  = (unsigned short*)(ws + 200 * MB);  // 2 MB
  unsigned short* adjT_bf = (unsigned short*)(ws + 202 * MB);  // 2 MB
  unsigned short* A2_bf   = (unsigned short*)(ws + 204 * MB);  // 2 MB
  unsigned short* A2T_bf  = (unsigned short*)(ws + 206 * MB);  // 2 MB
  float* sqpart           = (float*)(ws + 208 * MB);           // 16 MB (4 partials)
  float* agg1             = (float*)(ws + 200 * MB);           // 16 MB (overlaps consumed bufs)
  unsigned char* mcode    = (unsigned char*)(ws + 224 * MB);   // 1 MB
  unsigned int* entries   = (unsigned int*)(ws + 225 * MB);    // 64 KB
  int* nnz2               = (int*)(ws + 226 * MB);             // 4 B
  float* agg0 = out;  // d_out doubles as agg partial 0

  hipMemsetAsync(nnz2, 0, 4, stream);

  dim3 blk32(32, 8, 1);
  convert_wp<<<dim3(16, 16, 32), 256, 0, stream>>>(adjw, Wp_bf, WpT_bf);
  convert_x<<<dim3(4, 32, 32), blk32, 0, stream>>>(x, xT_bf);
  mask0cvt<<<dim3(32, 32, 1), blk32, 0, stream>>>(adj, mcode, adj_bf, adjT_bf);

  // A^2: K-split 4, exact integer partials, plain stores
  gemm_lds<3><<<dim3(8, 8, 4), 256, 0, stream>>>(
      adj_bf, (size_t)0, adjT_bf, (size_t)0, 0, 4, 8, EpiSqPart{sqpart});
  scan_a2<<<dim3(32, 32, 1), blk32, 0, stream>>>(sqpart, A2_bf, A2T_bf, mcode);
  // A^4: K-split 4 (A^2 ints < 256 exact in bf16)
  gemm_lds<3><<<dim3(8, 8, 4), 256, 0, stream>>>(
      A2_bf, (size_t)0, A2T_bf, (size_t)0, 0, 4, 8, EpiSqPart{sqpart});
  scan_a4<<<dim3(4096, 1, 1), 256, 0, stream>>>(sqpart, entries, nnz2);

  // big batched gemm: WcombT = mask2 .* (Wp^2)^T  (batch->XCD swizzle)
  gemm_lds<3><<<dim3(8, 8, 32), 256, 0, stream>>>(
      WpT_bf, NNNN, Wp_bf, NNNN, 2, 1, NN / BK, EpiWcomb{mcode, WcombT});

  hop2_fix<<<dim3(32, 8, 1), 256, 0, stream>>>(Wp_bf, WpT_bf, nnz2, entries, WcombT);

  // agg = (WcombT + mask1^T.*WpT) @ x — K-split 2 partials (batch->XCD swizzle)
  gemm_pipe<2, true><<<dim3(8, 1, 64), 256, 0, stream>>>(
      WcombT, NNNN, WpT_bf, mcode, xT_bf, (size_t)DD * NN, 2, 2, 16,
      EpiAggPart{agg0, agg1});

  fused_out<<<dim3(2048, 1, 1), 256, 0, stream>>>(agg0, agg1, x, W, bias, a2, b2, out);
}

// Round 6
// 474.103 us; speedup vs baseline: 1.1014x; 1.0075x over previous
//
#include <hip/hip_runtime.h>

#define NN 1024
#define BB 32
#define DD 128
#define EPSF 1e-6f
#define CAP 16384
#define NNNN ((size_t)NN * NN)

typedef __bf16 bf16x8 __attribute__((ext_vector_type(8)));
typedef float  f32x4  __attribute__((ext_vector_type(4)));
typedef unsigned short u16x8 __attribute__((ext_vector_type(8)));

typedef __attribute__((address_space(3))) unsigned int lds_u32;
typedef __attribute__((address_space(1))) const unsigned int glb_u32;

__device__ __forceinline__ lds_u32* lds_cast(const void* p) {
  return (lds_u32*)(unsigned int)(unsigned long long)p;
}
__device__ __forceinline__ glb_u32* glb_cast(const void* p) {
  return (glb_u32*)(unsigned long long)p;
}

__device__ __forceinline__ float bf2f(unsigned short u) {
  union { unsigned int i; float f; } v; v.i = ((unsigned int)u) << 16; return v.f;
}
__device__ __forceinline__ unsigned short f2bf(float f) {
  union { float f; unsigned int i; } v; v.f = f;
  unsigned int r = v.i + 0x7fffu + ((v.i >> 16) & 1u);
  return (unsigned short)(r >> 16);
}

// ---------------- convert / transpose kernels ----------------

__global__ __launch_bounds__(256) void convert_wp(const float* __restrict__ src,
    unsigned short* __restrict__ Wp, unsigned short* __restrict__ WpT) {
  __shared__ float tile[64][65];
  const int b = blockIdx.z;
  const int c0 = blockIdx.x * 64, r0 = blockIdx.y * 64;
  const int t = threadIdx.x;
  const int rr = t >> 3, cb = (t & 7) * 8;
  const size_t base = (size_t)b * NNNN;
#pragma unroll
  for (int p = 0; p < 2; ++p) {
    const int r = rr + p * 32;
    const float* srow = src + base + (size_t)(r0 + r) * NN + c0 + cb;
    f32x4 v0 = *(const f32x4*)srow;
    f32x4 v1 = *(const f32x4*)(srow + 4);
    u16x8 w;
#pragma unroll
    for (int j = 0; j < 4; ++j) { w[j] = f2bf(v0[j]); w[4 + j] = f2bf(v1[j]); }
    *(u16x8*)(Wp + base + (size_t)(r0 + r) * NN + c0 + cb) = w;
#pragma unroll
    for (int j = 0; j < 4; ++j) { tile[r][cb + j] = v0[j]; tile[r][cb + 4 + j] = v1[j]; }
  }
  __syncthreads();
#pragma unroll
  for (int p = 0; p < 2; ++p) {
    const int r = rr + p * 32;
    u16x8 w;
#pragma unroll
    for (int j = 0; j < 8; ++j) w[j] = f2bf(tile[cb + j][r]);
    *(u16x8*)(WpT + base + (size_t)(c0 + r) * NN + r0 + cb) = w;
  }
}

__global__ __launch_bounds__(256) void convert_x(const float* __restrict__ x,
    unsigned short* __restrict__ xT) {
  __shared__ float tile[32][33];
  const int b = blockIdx.z;
  const int d0 = blockIdx.x * 32, n0 = blockIdx.y * 32;
  const int tx = threadIdx.x, ty = threadIdx.y;
#pragma unroll
  for (int s = 0; s < 4; ++s) {
    int rr = ty + s * 8;
    tile[rr][tx] = x[(size_t)b * NN * DD + (size_t)(n0 + rr) * DD + d0 + tx];
  }
  __syncthreads();
#pragma unroll
  for (int s = 0; s < 4; ++s) {
    int rr = ty + s * 8;
    xT[(size_t)b * DD * NN + (size_t)(d0 + rr) * NN + n0 + tx] = f2bf(tile[tx][rr]);
  }
}

// adj -> mcode bit0 (= adj[j,i]==1 at [i,j]), adj_bf, adjT_bf
__global__ __launch_bounds__(256) void mask0cvt(const float* __restrict__ adj,
    unsigned char* __restrict__ mcode, unsigned short* __restrict__ adjbf,
    unsigned short* __restrict__ adjTbf) {
  __shared__ float tile[32][33];
  const int i0 = blockIdx.x * 32, j0 = blockIdx.y * 32;
  const int tx = threadIdx.x, ty = threadIdx.y;
#pragma unroll
  for (int s = 0; s < 4; ++s) {
    int rr = ty + s * 8;
    float v = adj[(size_t)(j0 + rr) * NN + i0 + tx];
    adjbf[(size_t)(j0 + rr) * NN + i0 + tx] = f2bf(v);
    tile[rr][tx] = v;
  }
  __syncthreads();
#pragma unroll
  for (int s = 0; s < 4; ++s) {
    int rr = ty + s * 8;
    float v = tile[tx][rr];
    adjTbf[(size_t)(i0 + rr) * NN + j0 + tx] = f2bf(v);
    mcode[(size_t)(i0 + rr) * NN + j0 + tx] = (v == 1.0f) ? 1 : 0;
  }
}

// sum 4 K-split partials (exact ints) -> A2 bf16, A2T bf16, mcode bit1 where ==1
__global__ __launch_bounds__(256) void scan_a2(const float* __restrict__ P,
    unsigned short* __restrict__ A2, unsigned short* __restrict__ A2T,
    unsigned char* __restrict__ mcode) {
  __shared__ float tile[32][33];
  const int m0 = blockIdx.x * 32, n0 = blockIdx.y * 32;
  const int tx = threadIdx.x, ty = threadIdx.y;
#pragma unroll
  for (int s = 0; s < 4; ++s) {
    int rr = ty + s * 8;
    size_t idx = (size_t)(m0 + rr) * NN + n0 + tx;
    float v = P[idx] + P[NNNN + idx] + P[2 * NNNN + idx] + P[3 * NNNN + idx];
    A2[idx] = f2bf(v);
    tile[rr][tx] = v;
  }
  __syncthreads();
#pragma unroll
  for (int s = 0; s < 4; ++s) {
    int rr = ty + s * 8;
    float v = tile[tx][rr];
    A2T[(size_t)(n0 + rr) * NN + m0 + tx] = f2bf(v);
    if (v == 1.0f) mcode[(size_t)(n0 + rr) * NN + m0 + tx] |= 2;
  }
}

// sum 4 partials of A^4; record entries (m<<16)|n where ==1.0
__global__ __launch_bounds__(256) void scan_a4(const float* __restrict__ P,
    unsigned int* __restrict__ entries, int* __restrict__ nnz) {
  size_t e = (size_t)blockIdx.x * 256 + threadIdx.x;
  float v = P[e] + P[NNNN + e] + P[2 * NNNN + e] + P[3 * NNNN + e];
  if (v == 1.0f) {
    int idx = atomicAdd(nnz, 1);
    if (idx < CAP) entries[idx] = ((unsigned)(e >> 10) << 16) | (unsigned)(e & 1023);
  }
}

// ---------------- MFMA GEMM tiles ----------------
// C[m,n] = sum_k A[m,k]*B[n,k].
#define BM 128
#define BN 128
#define BK 32

struct EpiWcomb {  // mask2-gated bf16 write
  const unsigned char* mc;
  unsigned short* out;
  __device__ __forceinline__ void operator()(int b, int ks, int i, int j, float v) const {
    size_t idx = (size_t)i * NN + j;
    out[(size_t)b * NNNN + idx] = (mc[idx] & 2) ? f2bf(v) : (unsigned short)0;
  }
};

struct EpiSqPart {  // K-split partial, plain store
  float* buf;
  __device__ __forceinline__ void operator()(int b, int ks, int i, int j, float v) const {
    buf[(size_t)ks * NNNN + (size_t)i * NN + j] = v;
  }
};

struct EpiAggPart {  // 2-way K-split partials (p0 = d_out, p1 = ws)
  float* p0;
  float* p1;
  __device__ __forceinline__ void operator()(int b, int ks, int i, int d, float v) const {
    (ks ? p1 : p0)[(size_t)b * NN * DD + (size_t)i * DD + d] = v;
  }
};

#define LGKM_BARRIER() do { \
  asm volatile("s_waitcnt lgkmcnt(0)" ::: "memory"); \
  __builtin_amdgcn_s_barrier(); \
  asm volatile("" ::: "memory"); } while (0)

// ================= 256x256 8-wave deep-pipelined GEMM (template port) =======
// All 2-phase-class 128^2 structures plateaued at MfmaUtil~23% (MFMA-busy
// invariant ~28us) — the documented 2-phase structural ceiling (m233). This is
// the 8-phase-class schedule: 8 waves (2Mx4N), 256^2 tile, BK=32, FOUR-slot
// LDS ring (128KB, 1 block/CU). Per K-tile: vmcnt(8)+barrier at top (counted,
// never 0 mid-loop — tile kt+3 staged during kt => ~3 windows latency cover),
// then two {stage-half || ds_read || setprio-wrapped 16-MFMA} phases. bf frags
// loaded once per tile, reused across both MFMA clusters.
// vmcnt ledger (per thread, 2 loads per stageA/stageB):
//   prologue issues A0 B0 A1 B1 A2 B2; tile kt issues A(kt+3),B(kt+3).
//   top of kt (kt<=nit-3): newest 8 loads = A/B(kt+1),A/B(kt+2) => vmcnt(8)
//   guarantees A(kt),B(kt) landed. kt==nit-2: vmcnt(4). kt==nit-1: vmcnt(0).
// WAR: stage into slot (kt+3)&3 = (kt-1)&3; tile kt-1's last ds_reads complete
// before each wave's P2 MFMAs (lgkmcnt), which precede the top-of-kt barrier.
#define TBM 256
#define TBN 256
#define TBK 32

template <typename Epi>
__global__ __launch_bounds__(512, 2) void gemm8(
    const unsigned short* __restrict__ Ap, size_t sA,
    const unsigned short* __restrict__ Bp, size_t sB,
    int swz, int ksN, int nit, Epi epi) {
  __shared__ __align__(16) unsigned short As[4 * TBM * TBK];  // 64 KB
  __shared__ __align__(16) unsigned short Bs[4 * TBN * TBK];  // 64 KB
  int bx = blockIdx.x, by = blockIdx.y, z = blockIdx.z;
  if (swz == 2) {  // grid (4,4,Z): 2 whole batches co-resident per XCD
    int lin = bx + (by << 2) + (z << 4);
    int xcd = lin & 7, rest = lin >> 3;          // rest in 0..(4*Z/8*... )
    z = (xcd << 2) + (rest >> 4);                // 4 batches per XCD (Z=32)
    int tile = rest & 15;
    bx = tile & 3; by = tile >> 2;
  }
  const int b = z / ksN, ks = z - b * ksN;
  const int kbase = ks * nit * TBK;
  const int tm = bx * TBM, tn = by * TBN;
  const unsigned short* Ab = Ap + (size_t)b * sA;
  const unsigned short* Bb = Bp + (size_t)b * sB;
  const int tid = threadIdx.x;
  const int w = tid >> 6, l = tid & 63;
  const int fr = l & 15, quad = l >> 4;
  const int wm = w >> 2, wn = w & 3;             // 2M x 4N wave grid
  const int kcq = (quad ^ ((fr >> 1) & 3)) * 8;  // swizzled granule for ds_read

  // staging: per operand-tile (256x32 = 16KB) each wave issues 2 gloads;
  // chunk c = i*8 + w covers rows c*16 + (l>>2), granule l&3. LDS dest linear;
  // global source granule pre-swizzled: (l&3) ^ ((l>>3)&3)  [(r>>1)&3 with
  // r = c*16 + (l>>2); c*16>>1 ≡ 0 mod 4].
  const int srow = l >> 2;
  const int sgr = (l & 3) ^ ((l >> 3) & 3);
  const unsigned short* gA0 = Ab + (size_t)(tm + w * 16 + srow) * NN + kbase + sgr * 8;
  const unsigned short* gA1 = gA0 + (size_t)128 * NN;
  const unsigned short* gB0 = Bb + (size_t)(tn + w * 16 + srow) * NN + kbase + sgr * 8;
  const unsigned short* gB1 = gB0 + (size_t)128 * NN;

  f32x4 acc[8][4];
#pragma unroll
  for (int mi = 0; mi < 8; ++mi)
#pragma unroll
    for (int ni = 0; ni < 4; ++ni) acc[mi][ni] = (f32x4){0.f, 0.f, 0.f, 0.f};

  auto stageA = [&](int kt) {
    unsigned short* base = As + (kt & 3) * (TBM * TBK);
    const size_t kk = (size_t)kt * TBK;
    __builtin_amdgcn_global_load_lds(glb_cast(gA0 + kk), lds_cast(base + (w * 16) * TBK), 16, 0, 0);
    __builtin_amdgcn_global_load_lds(glb_cast(gA1 + kk), lds_cast(base + ((8 + w) * 16) * TBK), 16, 0, 0);
  };
  auto stageB = [&](int kt) {
    unsigned short* base = Bs + (kt & 3) * (TBN * TBK);
    const size_t kk = (size_t)kt * TBK;
    __builtin_amdgcn_global_load_lds(glb_cast(gB0 + kk), lds_cast(base + (w * 16) * TBK), 16, 0, 0);
    __builtin_amdgcn_global_load_lds(glb_cast(gB1 + kk), lds_cast(base + ((8 + w) * 16) * TBK), 16, 0, 0);
  };

  // prologue: tiles 0,1,2 in flight (12 loads/thread)
  stageA(0); stageB(0);
  stageA(1); stageB(1);
  stageA(2); stageB(2);

#pragma unroll 1
  for (int kt = 0; kt < nit; ++kt) {
    if (kt < nit - 2) {
      asm volatile("s_waitcnt vmcnt(8)" ::: "memory");
    } else if (kt == nit - 2) {
      asm volatile("s_waitcnt vmcnt(4)" ::: "memory");
    } else {
      asm volatile("s_waitcnt vmcnt(0)" ::: "memory");
    }
    __builtin_amdgcn_sched_barrier(0);
    __builtin_amdgcn_s_barrier();   // tile kt visible to all; prior reads retired
    __builtin_amdgcn_sched_barrier(0);

    const unsigned short* Asl = As + (kt & 3) * (TBM * TBK);
    const unsigned short* Bsl = Bs + (kt & 3) * (TBN * TBK);

    // ---- phase 1: stage A(kt+3) || ds_read bf0-3,af0-3 || 16 MFMA ----
    if (kt + 3 < nit) stageA(kt + 3);
    bf16x8 bf[4], af[4];
#pragma unroll
    for (int ni = 0; ni < 4; ++ni)
      bf[ni] = *(const bf16x8*)(Bsl + (wn * 64 + ni * 16 + fr) * TBK + kcq);
#pragma unroll
    for (int mi = 0; mi < 4; ++mi)
      af[mi] = *(const bf16x8*)(Asl + (wm * 128 + mi * 16 + fr) * TBK + kcq);
    asm volatile("s_waitcnt lgkmcnt(0)" ::: "memory");
    __builtin_amdgcn_sched_barrier(0);
    __builtin_amdgcn_s_setprio(1);
#pragma unroll
    for (int mi = 0; mi < 4; ++mi)
#pragma unroll
      for (int ni = 0; ni < 4; ++ni)
        acc[mi][ni] = __builtin_amdgcn_mfma_f32_16x16x32_bf16(af[mi], bf[ni], acc[mi][ni], 0, 0, 0);
    __builtin_amdgcn_s_setprio(0);

    // ---- phase 2: stage B(kt+3) || ds_read af4-7 || 16 MFMA (bf reused) ----
    if (kt + 3 < nit) stageB(kt + 3);
#pragma unroll
    for (int mi = 0; mi < 4; ++mi)
      af[mi] = *(const bf16x8*)(Asl + (wm * 128 + (mi + 4) * 16 + fr) * TBK + kcq);
    asm volatile("s_waitcnt lgkmcnt(0)" ::: "memory");
    __builtin_amdgcn_sched_barrier(0);
    __builtin_amdgcn_s_setprio(1);
#pragma unroll
    for (int mi = 0; mi < 4; ++mi)
#pragma unroll
      for (int ni = 0; ni < 4; ++ni)
        acc[mi + 4][ni] = __builtin_amdgcn_mfma_f32_16x16x32_bf16(af[mi], bf[ni], acc[mi + 4][ni], 0, 0, 0);
    __builtin_amdgcn_s_setprio(0);
  }

  // C/D layout: col = lane&15, row = quad*4 + reg
#pragma unroll
  for (int mi = 0; mi < 8; ++mi)
#pragma unroll
    for (int ni = 0; ni < 4; ++ni)
#pragma unroll
      for (int t = 0; t < 4; ++t)
        epi(b, ks, tm + wm * 128 + mi * 16 + quad * 4 + t,
            tn + wn * 64 + ni * 16 + fr, acc[mi][ni][t]);
}

// ---- triple-buffered counted-vmcnt 128^2 GEMM (kept for small A^2/A^4) ----
template <int MW, typename Epi>
__global__ __launch_bounds__(256, MW) void gemm_lds(
    const unsigned short* __restrict__ Ap, size_t sA,
    const unsigned short* __restrict__ Bp, size_t sB,
    int swz, int ksN, int nit, Epi epi) {
  __shared__ __align__(16) unsigned short As[3 * BM * BK];  // 24 KB
  __shared__ __align__(16) unsigned short Bs[3 * BN * BK];  // 24 KB
  int bx = blockIdx.x, by = blockIdx.y, z = blockIdx.z;
  if (swz == 1) {
    int lin = bx + (by << 3);
    int r = lin & 7, s = lin >> 3;
    bx = ((r & 3) << 1) | (s & 1);
    by = ((r >> 2) << 2) | (s >> 1);
  }
  const int b = z / ksN, ks = z - b * ksN;
  const int kbase = ks * nit * BK;
  const int tm = bx * BM, tn = by * BN;
  const unsigned short* Ab = Ap + (size_t)b * sA;
  const unsigned short* Bb = Bp + (size_t)b * sB;
  const int tid = threadIdx.x;
  const int w = tid >> 6, l = tid & 63;
  const int fr = l & 15, quad = l >> 4;
  const int moff = (w & 1) * 64, noff = (w >> 1) * 64;

  const int sr = l >> 2, ss = l & 3;
  const int r0 = w * 16 + sr;
  const int r1 = 64 + w * 16 + sr;
  const int kc0 = ss ^ ((r0 >> 1) & 3);
  const int kc1 = ss ^ ((r1 >> 1) & 3);
  const unsigned short* gA0 = Ab + (size_t)(tm + r0) * NN + kbase + kc0 * 8;
  const unsigned short* gA1 = Ab + (size_t)(tm + r1) * NN + kbase + kc1 * 8;
  const unsigned short* gB0 = Bb + (size_t)(tn + r0) * NN + kbase + kc0 * 8;
  const unsigned short* gB1 = Bb + (size_t)(tn + r1) * NN + kbase + kc1 * 8;

  f32x4 acc[4][4];
#pragma unroll
  for (int mi = 0; mi < 4; ++mi)
#pragma unroll
    for (int ni = 0; ni < 4; ++ni) acc[mi][ni] = (f32x4){0.f, 0.f, 0.f, 0.f};

  auto stage = [&](int off, int kt) {
    const size_t kk = (size_t)kt * BK;
    __builtin_amdgcn_global_load_lds(glb_cast(gA0 + kk),
        lds_cast(As + off + (w * 16) * BK), 16, 0, 0);
    __builtin_amdgcn_global_load_lds(glb_cast(gA1 + kk),
        lds_cast(As + off + (64 + w * 16) * BK), 16, 0, 0);
    __builtin_amdgcn_global_load_lds(glb_cast(gB0 + kk),
        lds_cast(Bs + off + (w * 16) * BK), 16, 0, 0);
    __builtin_amdgcn_global_load_lds(glb_cast(gB1 + kk),
        lds_cast(Bs + off + (64 + w * 16) * BK), 16, 0, 0);
  };
  auto compute = [&](const unsigned short* Ad, const unsigned short* Bd) {
    bf16x8 af[4], bfr[4];
#pragma unroll
    for (int mi = 0; mi < 4; ++mi) {
      int r = moff + mi * 16 + fr;
      int kc = quad ^ ((r >> 1) & 3);
      af[mi] = *(const bf16x8*)(Ad + r * BK + kc * 8);
    }
#pragma unroll
    for (int ni = 0; ni < 4; ++ni) {
      int r = noff + ni * 16 + fr;
      int kc = quad ^ ((r >> 1) & 3);
      bfr[ni] = *(const bf16x8*)(Bd + r * BK + kc * 8);
    }
#pragma unroll
    for (int mi = 0; mi < 4; ++mi)
#pragma unroll
      for (int ni = 0; ni < 4; ++ni)
        acc[mi][ni] = __builtin_amdgcn_mfma_f32_16x16x32_bf16(af[mi], bfr[ni], acc[mi][ni], 0, 0, 0);
  };

  stage(0, 0);
  stage(BM * BK, 1);
  int o0 = 0, o1 = BM * BK, o2 = 2 * BM * BK;
#pragma unroll 1
  for (int kt = 0; kt < nit; ++kt) {
    if (kt + 1 < nit) {
      asm volatile("s_waitcnt vmcnt(4)" ::: "memory");
    } else {
      asm volatile("s_waitcnt vmcnt(0)" ::: "memory");
    }
    __builtin_amdgcn_sched_barrier(0);
    __builtin_amdgcn_s_barrier();
    if (kt + 2 < nit) stage(o2, kt + 2);
    compute(As + o0, Bs + o0);
    int t = o0; o0 = o1; o1 = o2; o2 = t;
  }

#pragma unroll
  for (int mi = 0; mi < 4; ++mi)
#pragma unroll
    for (int ni = 0; ni < 4; ++ni)
#pragma unroll
      for (int t = 0; t < 4; ++t)
        epi(b, ks, tm + moff + mi * 16 + quad * 4 + t, tn + noff + ni * 16 + fr, acc[mi][ni][t]);
}

// ---- reg-staged pipelined GEMM (kept for the COMB path, which must fold
// masked WpT into A during staging — global_load_lds can't transform data).
template <int MW, bool COMB, typename Epi>
__global__ __launch_bounds__(256, MW) void gemm_pipe(
    const unsigned short* __restrict__ Ap, size_t sA,
    const unsigned short* __restrict__ WtP, const unsigned char* __restrict__ McP,
    const unsigned short* __restrict__ Bp, size_t sB,
    int swz, int ksN, int nit, Epi epi) {
  __shared__ __align__(16) unsigned short As[2 * BM * BK];
  __shared__ __align__(16) unsigned short Bs[2 * BN * BK];
  int bx = blockIdx.x, by = blockIdx.y, z = blockIdx.z;
  if (swz == 1) {
    int lin = bx + (by << 3);
    int r = lin & 7, s = lin >> 3;
    bx = ((r & 3) << 1) | (s & 1);
    by = ((r >> 2) << 2) | (s >> 1);
  } else if (swz == 2) {
    int lin = bx + (z << 3);
    int xcd = lin & 7, q = lin >> 3;
    z = (xcd << 3) + (q >> 3);
    bx = q & 7;
  }
  const int b = z / ksN, ks = z - b * ksN;
  const int kbase = ks * nit * BK;
  const int tm = bx * BM, tn = by * BN;
  const unsigned short* Ab = Ap + (size_t)b * sA;
  const unsigned short* Bb = Bp + (size_t)b * sB;
  const unsigned short* Wb = COMB ? (WtP + (size_t)b * sA) : nullptr;
  const int tid = threadIdx.x;
  const int w = tid >> 6, l = tid & 63;
  const int lr = l >> 2, lc = l & 3;
  const int fr = l & 15, quad = l >> 4;
  const int moff = (w & 1) * 64, noff = (w >> 1) * 64;
  const int r0 = w * 16 + lr, r1 = (w + 4) * 16 + lr;
  const int kc0 = lc ^ ((r0 >> 1) & 3), kc1 = lc ^ ((r1 >> 1) & 3);
  const size_t ao0 = (size_t)(tm + r0) * NN + kbase + kc0 * 8;
  const size_t ao1 = (size_t)(tm + r1) * NN + kbase + kc1 * 8;
  const size_t bo0 = (size_t)(tn + r0) * NN + kbase + kc0 * 8;
  const size_t bo1 = (size_t)(tn + r1) * NN + kbase + kc1 * 8;
  const int ls0 = r0 * BK + lc * 8, ls1 = r1 * BK + lc * 8;

  unsigned short* const As0 = As;           unsigned short* const As1 = As + BM * BK;
  unsigned short* const Bs0 = Bs;           unsigned short* const Bs1 = Bs + BN * BK;

  f32x4 acc[4][4];
#pragma unroll
  for (int mi = 0; mi < 4; ++mi)
#pragma unroll
    for (int ni = 0; ni < 4; ++ni) acc[mi][ni] = (f32x4){0.f, 0.f, 0.f, 0.f};

  struct RegSet {
    u16x8 a0, a1, b0, b1;
    u16x8 w0, w1;
    unsigned long long m0, m1;
  };
  RegSet R0, R1;

  auto load = [&](RegSet& R, int kt) {
    size_t kk = (size_t)kt * BK;
    R.a0 = *(const u16x8*)(Ab + ao0 + kk);
    R.a1 = *(const u16x8*)(Ab + ao1 + kk);
    R.b0 = *(const u16x8*)(Bb + bo0 + kk);
    R.b1 = *(const u16x8*)(Bb + bo1 + kk);
    if constexpr (COMB) {
      R.w0 = *(const u16x8*)(Wb + ao0 + kk);
      R.w1 = *(const u16x8*)(Wb + ao1 + kk);
      R.m0 = *(const unsigned long long*)(McP + ao0 + kk);
      R.m1 = *(const unsigned long long*)(McP + ao1 + kk);
    }
  };
  auto wr = [&](const RegSet& R, unsigned short* Ad, unsigned short* Bd) {
    if constexpr (COMB) {
      u16x8 f0, f1;
#pragma unroll
      for (int j = 0; j < 8; ++j) {
        float s0 = bf2f(R.a0[j]);
        if ((R.m0 >> (8 * j)) & 1ull) s0 += bf2f(R.w0[j]);
        f0[j] = f2bf(s0);
        float s1 = bf2f(R.a1[j]);
        if ((R.m1 >> (8 * j)) & 1ull) s1 += bf2f(R.w1[j]);
        f1[j] = f2bf(s1);
      }
      *(u16x8*)(Ad + ls0) = f0;
      *(u16x8*)(Ad + ls1) = f1;
    } else {
      *(u16x8*)(Ad + ls0) = R.a0;
      *(u16x8*)(Ad + ls1) = R.a1;
    }
    *(u16x8*)(Bd + ls0) = R.b0;
    *(u16x8*)(Bd + ls1) = R.b1;
  };
  auto compute = [&](const unsigned short* Ad, const unsigned short* Bd) {
    bf16x8 af[4], bfr[4];
#pragma unroll
    for (int mi = 0; mi < 4; ++mi) {
      int r = moff + mi * 16 + fr;
      int kc = quad ^ ((r >> 1) & 3);
      af[mi] = *(const bf16x8*)(Ad + r * BK + kc * 8);
    }
#pragma unroll
    for (int ni = 0; ni < 4; ++ni) {
      int r = noff + ni * 16 + fr;
      int kc = quad ^ ((r >> 1) & 3);
      bfr[ni] = *(const bf16x8*)(Bd + r * BK + kc * 8);
    }
#pragma unroll
    for (int mi = 0; mi < 4; ++mi)
#pragma unroll
      for (int ni = 0; ni < 4; ++ni)
        acc[mi][ni] = __builtin_amdgcn_mfma_f32_16x16x32_bf16(af[mi], bfr[ni], acc[mi][ni], 0, 0, 0);
  };

  load(R0, 0);
  load(R1, 1);
  wr(R0, As0, Bs0);
  load(R0, 2);
  LGKM_BARRIER();
#pragma unroll 1
  for (int kt = 0; kt < nit - 2; kt += 2) {
    compute(As0, Bs0);
    wr(R1, As1, Bs1);
    if (kt + 3 < nit) load(R1, kt + 3);
    LGKM_BARRIER();
    compute(As1, Bs1);
    wr(R0, As0, Bs0);
    if (kt + 4 < nit) load(R0, kt + 4);
    LGKM_BARRIER();
  }
  compute(As0, Bs0);
  wr(R1, As1, Bs1);
  LGKM_BARRIER();
  compute(As1, Bs1);

#pragma unroll
  for (int mi = 0; mi < 4; ++mi)
#pragma unroll
    for (int ni = 0; ni < 4; ++ni)
#pragma unroll
      for (int t = 0; t < 4; ++t)
        epi(b, ks, tm + moff + mi * 16 + quad * 4 + t, tn + noff + ni * 16 + fr, acc[mi][ni][t]);
}

// ---------------- gated hop-2 sparse fixup (expected: nnz==0, exits) ----------------
__global__ __launch_bounds__(256) void hop2_fix(const unsigned short* __restrict__ Wp,
    const unsigned short* __restrict__ WpT, const int* __restrict__ nnz,
    const unsigned int* __restrict__ entries, unsigned short* __restrict__ WcombT) {
  int n = *nnz;
  if (n > CAP) n = CAP;
  if (n == 0) return;
  __shared__ float rbuf[256];
  const int b = blockIdx.x;
  const size_t bnn = (size_t)b * NNNN;
  for (int e = blockIdx.y; e < n; e += gridDim.y) {
    unsigned int ent = entries[e];
    int j = ent >> 16, i = ent & 0xFFFF;
    float s = 0.f;
    for (int k = threadIdx.x; k < NN; k += 256) {
      float u = 0.f, v = 0.f;
      const unsigned short* wj  = Wp  + bnn + (size_t)j * NN;
      const unsigned short* wtk = WpT + bnn + (size_t)k * NN;
      const unsigned short* wk  = Wp  + bnn + (size_t)k * NN;
      const unsigned short* wti = WpT + bnn + (size_t)i * NN;
      for (int t = 0; t < NN; ++t) {
        u += bf2f(wj[t]) * bf2f(wtk[t]);
        v += bf2f(wk[t]) * bf2f(wti[t]);
      }
      s += u * v;
    }
    rbuf[threadIdx.x] = s;
    __syncthreads();
    for (int off = 128; off > 0; off >>= 1) {
      if (threadIdx.x < off) rbuf[threadIdx.x] += rbuf[threadIdx.x + off];
      __syncthreads();
    }
    if (threadIdx.x == 0) {
      size_t idx = bnn + (size_t)i * NN + j;
      WcombT[idx] = f2bf(bf2f(WcombT[idx]) + rbuf[0]);
    }
    __syncthreads();
  }
}

// ---------------- fused (sum 2 agg partials) + Linear + residual + LayerNorm ----------------
#define FROWS 16
__global__ __launch_bounds__(256) void fused_out(const float* __restrict__ a0p,
    const float* __restrict__ a1p, const float* __restrict__ x,
    const float* __restrict__ W, const float* __restrict__ bias,
    const float* __restrict__ g2, const float* __restrict__ bsh,
    float* __restrict__ out) {
  __shared__ unsigned short Wl[128 * 136];
  __shared__ float ar[256];
  __shared__ float wred[8];
  const int tid = threadIdx.x;
  for (int e = tid; e < 16384; e += 256) Wl[(e >> 7) * 136 + (e & 127)] = f2bf(W[e]);
  const int half = tid >> 7, o = tid & 127;
  const int w = tid >> 6, lane = tid & 63;
  const float bo = bias[o], go = g2[o], b2o = bsh[o];
  const size_t row0 = (size_t)blockIdx.x * FROWS;
  size_t rb = row0 * DD;
  float av = a0p[rb + tid] + a1p[rb + tid];
  float xv = x[rb + tid];
  __syncthreads();  // Wl ready
  for (int rr = 0; rr < FROWS; rr += 2) {
    ar[tid] = av;
    const float xcur = xv;
    const size_t rbc = (row0 + rr) * DD;
    __syncthreads();  // ar ready
    if (rr + 2 < FROWS) {
      size_t rb2 = (row0 + rr + 2) * DD;
      av = a0p[rb2 + tid] + a1p[rb2 + tid];
      xv = x[rb2 + tid];
    }
    float hv = bo + xcur;
    const unsigned short* wrow = &Wl[o * 136];
    const float* arow = &ar[half * 128];
#pragma unroll
    for (int d8 = 0; d8 < 16; ++d8) {
      bf16x8 wv = *(const bf16x8*)(wrow + d8 * 8);
#pragma unroll
      for (int t = 0; t < 8; ++t) hv += (float)wv[t] * arow[d8 * 8 + t];
    }
    float s = hv, q = hv * hv;
#pragma unroll
    for (int off = 32; off > 0; off >>= 1) {
      s += __shfl_xor(s, off);
      q += __shfl_xor(q, off);
    }
    if (lane == 0) { wred[w] = s; wred[4 + w] = q; }
    __syncthreads();  // wred ready (also gates ar overwrite next iter)
    float st = wred[half * 2] + wred[half * 2 + 1];
    float qt = wred[4 + half * 2] + wred[4 + half * 2 + 1];
    float mean = st * (1.0f / 128.0f);
    float var = (qt - 128.0f * mean * mean) * (1.0f / 127.0f);
    var = fmaxf(var, 0.0f);
    float stdv = sqrtf(var);
    out[rbc + tid] = go * (hv - mean) / (stdv + EPSF) + b2o;
  }
}

// ---------------- launch ----------------
extern "C" void kernel_launch(void* const* d_in, const int* in_sizes, int n_in,
                              void* d_out, int out_size, void* d_ws, size_t ws_size,
                              hipStream_t stream) {
  (void)in_sizes; (void)n_in; (void)out_size; (void)ws_size;
  const float* x    = (const float*)d_in[0];
  const float* adjw = (const float*)d_in[1];
  const float* adj  = (const float*)d_in[2];
  const float* W    = (const float*)d_in[3];
  const float* bias = (const float*)d_in[4];
  const float* a2   = (const float*)d_in[5];
  const float* b2   = (const float*)d_in[6];
  float* out = (float*)d_out;

  char* ws = (char*)d_ws;
  const size_t MB = 1048576;
  unsigned short* Wp_bf   = (unsigned short*)(ws);             // 64 MB
  unsigned short* WpT_bf  = (unsigned short*)(ws + 64 * MB);   // 64 MB
  unsigned short* WcombT  = (unsigned short*)(ws + 128 * MB);  // 64 MB
  unsigned short* xT_bf   = (unsigned short*)(ws + 192 * MB);  // 8 MB
  unsigned short* adj_bf  = (unsigned short*)(ws + 200 * MB);  // 2 MB
  unsigned short* adjT_bf = (unsigned short*)(ws + 202 * MB);  // 2 MB
  unsigned short* A2_bf   = (unsigned short*)(ws + 204 * MB);  // 2 MB
  unsigned short* A2T_bf  = (unsigned short*)(ws + 206 * MB);  // 2 MB
  float* sqpart           = (float*)(ws + 208 * MB);           // 16 MB (4 partials)
  float* agg1             = (float*)(ws + 200 * MB);           // 16 MB (overlaps consumed bufs)
  unsigned char* mcode    = (unsigned char*)(ws + 224 * MB);   // 1 MB
  unsigned int* entries   = (unsigned int*)(ws + 225 * MB);    // 64 KB
  int* nnz2               = (int*)(ws + 226 * MB);             // 4 B
  float* agg0 = out;  // d_out doubles as agg partial 0

  hipMemsetAsync(nnz2, 0, 4, stream);

  dim3 blk32(32, 8, 1);
  convert_wp<<<dim3(16, 16, 32), 256, 0, stream>>>(adjw, Wp_bf, WpT_bf);
  convert_x<<<dim3(4, 32, 32), blk32, 0, stream>>>(x, xT_bf);
  mask0cvt<<<dim3(32, 32, 1), blk32, 0, stream>>>(adj, mcode, adj_bf, adjT_bf);

  // A^2: K-split 4, exact integer partials, plain stores
  gemm_lds<3><<<dim3(8, 8, 4), 256, 0, stream>>>(
      adj_bf, (size_t)0, adjT_bf, (size_t)0, 0, 4, 8, EpiSqPart{sqpart});
  scan_a2<<<dim3(32, 32, 1), blk32, 0, stream>>>(sqpart, A2_bf, A2T_bf, mcode);
  // A^4: K-split 4 (A^2 ints < 256 exact in bf16)
  gemm_lds<3><<<dim3(8, 8, 4), 256, 0, stream>>>(
      A2_bf, (size_t)0, A2T_bf, (size_t)0, 0, 4, 8, EpiSqPart{sqpart});
  scan_a4<<<dim3(4096, 1, 1), 256, 0, stream>>>(sqpart, entries, nnz2);

  // big batched gemm: WcombT = mask2 .* (Wp^2)^T — 256^2 8-wave deep pipeline,
  // batch->XCD swizzle (2 whole batches co-resident per XCD for L2 reuse)
  gemm8<<<dim3(4, 4, 32), 512, 0, stream>>>(
      WpT_bf, NNNN, Wp_bf, NNNN, 2, 1, NN / TBK, EpiWcomb{mcode, WcombT});

  hop2_fix<<<dim3(32, 8, 1), 256, 0, stream>>>(Wp_bf, WpT_bf, nnz2, entries, WcombT);

  // agg = (WcombT + mask1^T.*WpT) @ x — K-split 2 partials (batch->XCD swizzle)
  gemm_pipe<2, true><<<dim3(8, 1, 64), 256, 0, stream>>>(
      WcombT, NNNN, WpT_bf, mcode, xT_bf, (size_t)DD * NN, 2, 2, 16,
      EpiAggPart{agg0, agg1});

  fused_out<<<dim3(2048, 1, 1), 256, 0, stream>>>(agg0, agg1, x, W, bias, a2, b2, out);
}